// Round 1
// baseline (14687.283 us; speedup 1.0000x reference)
//
#include <hip/hip_runtime.h>

constexpr int Bn = 2, Cn = 128, FH = 96, FW = 160, Hh = 384, Wh = 640;
constexpr int HWl = FH * FW;   // 15360
constexpr int NHd = 4, NPt = 9;

#define DEVINL __device__ __forceinline__

template<int ACT> DEVINL float activ(float v) {
  if (ACT == 1) return v >= 0.f ? v : 0.1f * v;                       // leaky relu
  if (ACT == 2) return 0.5f * v * (1.f + erff(v * 0.70710678118654752f)); // exact gelu
  if (ACT == 3) return 1.f / (1.f + expf(-v));                        // sigmoid
  return v;
}

// ---------------------------------------------------------------------------
// Warp feat1/feat2 by (downsampled, scaled) flows; build fused concat + source
// flow factor: resize avg(2x2)=0.25*sum, *0.25 (scale), *0.5 (T) -> 0.03125*sum
// align_corners=True grid_sample with Wv==w  =>  sample pos = pixel + flow
// ---------------------------------------------------------------------------
__global__ __launch_bounds__(256) void k_warp_fuse(
    const float* __restrict__ feat1, const float* __restrict__ feat2,
    const float* __restrict__ flowf, const float* __restrict__ flowb,
    const float* __restrict__ edge1, const float* __restrict__ edge2,
    float* __restrict__ fused, float* __restrict__ source)
{
  int idx = blockIdx.x * blockDim.x + threadIdx.x;
  if (idx >= Bn * HWl) return;
  int j = idx % FW;
  int i = (idx / FW) % FH;
  int b = idx / HWl;

  const int y4 = 4 * i + 1, x4 = 4 * j + 1;
  const float* p;
  p = flowf + (size_t)((b * 2 + 0) * Hh + y4) * Wh + x4;
  float fx1 = 0.03125f * (p[0] + p[1] + p[Wh] + p[Wh + 1]);
  p = flowf + (size_t)((b * 2 + 1) * Hh + y4) * Wh + x4;
  float fy1 = 0.03125f * (p[0] + p[1] + p[Wh] + p[Wh + 1]);
  p = flowb + (size_t)((b * 2 + 0) * Hh + y4) * Wh + x4;
  float fx2 = 0.03125f * (p[0] + p[1] + p[Wh] + p[Wh + 1]);
  p = flowb + (size_t)((b * 2 + 1) * Hh + y4) * Wh + x4;
  float fy2 = 0.03125f * (p[0] + p[1] + p[Wh] + p[Wh + 1]);
  p = edge1 + (size_t)(b * Hh + y4) * Wh + x4;
  float e1 = 0.25f * (p[0] + p[1] + p[Wh] + p[Wh + 1]);
  p = edge2 + (size_t)(b * Hh + y4) * Wh + x4;
  float e2 = 0.25f * (p[0] + p[1] + p[Wh] + p[Wh + 1]);

  float sx1 = fminf(fmaxf((float)j + fx1, 0.f), (float)(FW - 1));
  float sy1 = fminf(fmaxf((float)i + fy1, 0.f), (float)(FH - 1));
  float sx2 = fminf(fmaxf((float)j + fx2, 0.f), (float)(FW - 1));
  float sy2 = fminf(fmaxf((float)i + fy2, 0.f), (float)(FH - 1));

  int x10 = (int)floorf(sx1), y10 = (int)floorf(sy1);
  int x11 = min(x10 + 1, FW - 1), y11 = min(y10 + 1, FH - 1);
  float wx1 = sx1 - (float)x10, wy1 = sy1 - (float)y10;
  int x20 = (int)floorf(sx2), y20 = (int)floorf(sy2);
  int x21 = min(x20 + 1, FW - 1), y21 = min(y20 + 1, FH - 1);
  float wx2 = sx2 - (float)x20, wy2 = sy2 - (float)y20;

  float a00 = (1.f - wx1) * (1.f - wy1), a01 = wx1 * (1.f - wy1);
  float a10 = (1.f - wx1) * wy1,         a11 = wx1 * wy1;
  float c00 = (1.f - wx2) * (1.f - wy2), c01 = wx2 * (1.f - wy2);
  float c10 = (1.f - wx2) * wy2,         c11 = wx2 * wy2;
  int o00 = y10 * FW + x10, o01 = y10 * FW + x11, o10 = y11 * FW + x10, o11 = y11 * FW + x11;
  int q00 = y20 * FW + x20, q01 = y20 * FW + x21, q10 = y21 * FW + x20, q11 = y21 * FW + x21;

  int pix = i * FW + j;
  for (int c = 0; c < Cn; ++c) {
    const float* f1 = feat1 + (size_t)(b * Cn + c) * HWl;
    const float* f2 = feat2 + (size_t)(b * Cn + c) * HWl;
    float v1 = f1[o00] * a00 + f1[o01] * a01 + f1[o10] * a10 + f1[o11] * a11;
    float v2 = f2[q00] * c00 + f2[q01] * c01 + f2[q10] * c10 + f2[q11] * c11;
    fused[(size_t)(b * 259 + c) * HWl + pix] = v1;
    fused[(size_t)(b * 259 + 128 + c) * HWl + pix] = v2;
    source[(size_t)(b * Cn + c) * HWl + pix] = 0.5f * (v1 + v2);
  }
  fused[(size_t)(b * 259 + 256) * HWl + pix] = e1;
  fused[(size_t)(b * 259 + 257) * HWl + pix] = e2;
  fused[(size_t)(b * 259 + 258) * HWl + pix] = 0.5f;  // tmap = T
}

// ---------------------------------------------------------------------------
// Generic 3x3 conv (pad=1, optional groups, row-windowed in/out buffers).
// in buffer holds global rows [in_r0, in_r0+in_rows); out holds [out_r0, +out_rows).
// Computes global output rows [ogr0, ogr1). Rows outside [0,Htot) are zero-pad.
// Each thread computes 4 consecutive j outputs. W must be a multiple of 4.
// ---------------------------------------------------------------------------
template<int ACT>
__global__ __launch_bounds__(256) void k_conv3x3(
    const float* __restrict__ in, const float* __restrict__ wt,
    const float* __restrict__ bias, float* __restrict__ out,
    int B, int Cin, int Cout, int W, int Htot,
    int in_r0, int in_rows, int out_r0, int out_rows,
    int ogr0, int ogr1, int cin_g, int cout_g)
{
  int JQ = W >> 2;
  int nrows = ogr1 - ogr0;
  int total = B * Cout * nrows * JQ;
  int idx = blockIdx.x * blockDim.x + threadIdx.x;
  if (idx >= total) return;
  int q = idx % JQ;
  int t1 = idx / JQ;
  int r = t1 % nrows + ogr0;
  int t2 = t1 / nrows;
  int co = t2 % Cout;
  int b = t2 / Cout;
  int j0 = q << 2;

  float bv = bias[co];
  float acc0 = bv, acc1 = bv, acc2 = bv, acc3 = bv;
  int cib = (co / cout_g) * cin_g;
  const float* wbase = wt + (size_t)co * cin_g * 9;

  for (int cl = 0; cl < cin_g; ++cl) {
    const float* wp = wbase + cl * 9;
    float wk[9];
#pragma unroll
    for (int k = 0; k < 9; ++k) wk[k] = wp[k];
    const float* ibase = in + (size_t)(b * Cin + cib + cl) * in_rows * W;
#pragma unroll
    for (int dy = 0; dy < 3; ++dy) {
      int gr = r + dy - 1;
      if (gr >= 0 && gr < Htot) {
        const float* ip = ibase + (size_t)(gr - in_r0) * W;
        float4 m = *reinterpret_cast<const float4*>(ip + j0);
        float v0 = (j0 > 0) ? ip[j0 - 1] : 0.f;
        float v5 = (j0 + 4 < W) ? ip[j0 + 4] : 0.f;
        float wa = wk[dy * 3], wb = wk[dy * 3 + 1], wc = wk[dy * 3 + 2];
        acc0 += wa * v0  + wb * m.x + wc * m.y;
        acc1 += wa * m.x + wb * m.y + wc * m.z;
        acc2 += wa * m.y + wb * m.z + wc * m.w;
        acc3 += wa * m.z + wb * m.w + wc * v5;
      }
    }
  }
  float4 res;
  res.x = activ<ACT>(acc0); res.y = activ<ACT>(acc1);
  res.z = activ<ACT>(acc2); res.w = activ<ACT>(acc3);
  float* op = out + ((size_t)(b * Cout + co) * out_rows + (r - out_r0)) * W + j0;
  *reinterpret_cast<float4*>(op) = res;
}

// ---------------------------------------------------------------------------
// 1x1 conv; optional residual-add into out (out += conv) when RES=1.
// ---------------------------------------------------------------------------
template<int ACT, int RES>
__global__ __launch_bounds__(256) void k_conv1x1(
    const float* __restrict__ in, const float* __restrict__ wt,
    const float* __restrict__ bias, float* __restrict__ out,
    int B, int Cin, int Cout, int HW)
{
  int NQ = HW >> 2;
  int total = B * Cout * NQ;
  int idx = blockIdx.x * blockDim.x + threadIdx.x;
  if (idx >= total) return;
  int q = idx % NQ;
  int t1 = idx / NQ;
  int co = t1 % Cout;
  int b = t1 / Cout;
  int j0 = q << 2;

  float bv = bias[co];
  float a0 = bv, a1 = bv, a2 = bv, a3 = bv;
  const float* ip = in + (size_t)b * Cin * HW + j0;
  const float* wp = wt + (size_t)co * Cin;
  for (int ci = 0; ci < Cin; ++ci) {
    float4 v = *reinterpret_cast<const float4*>(ip + (size_t)ci * HW);
    float wv = wp[ci];
    a0 += wv * v.x; a1 += wv * v.y; a2 += wv * v.z; a3 += wv * v.w;
  }
  float4 res;
  res.x = activ<ACT>(a0); res.y = activ<ACT>(a1);
  res.z = activ<ACT>(a2); res.w = activ<ACT>(a3);
  float* op = out + (size_t)(b * Cout + co) * HW + j0;
  if (RES) {
    float4 pv = *reinterpret_cast<const float4*>(op);
    res.x += pv.x; res.y += pv.y; res.z += pv.z; res.w += pv.w;
  }
  *reinterpret_cast<float4*>(op) = res;
}

// ---------------------------------------------------------------------------
// GroupNorm: one block per (b, group); 8 groups of 16 channels.
// ---------------------------------------------------------------------------
__global__ __launch_bounds__(256) void k_groupnorm(
    const float* __restrict__ x, const float* __restrict__ gw,
    const float* __restrict__ gb, float* __restrict__ q)
{
  const int cpg = 16;
  int b = blockIdx.x >> 3;
  int g = blockIdx.x & 7;
  const float* base = x + (size_t)(b * Cn + g * cpg) * HWl;
  const int n = cpg * HWl;
  double s = 0.0, s2 = 0.0;
  for (int t = threadIdx.x; t < n; t += 256) {
    float v = base[t];
    s += v; s2 += (double)v * (double)v;
  }
  __shared__ double sh1[256], sh2[256];
  sh1[threadIdx.x] = s; sh2[threadIdx.x] = s2;
  __syncthreads();
  for (int st = 128; st > 0; st >>= 1) {
    if (threadIdx.x < st) {
      sh1[threadIdx.x] += sh1[threadIdx.x + st];
      sh2[threadIdx.x] += sh2[threadIdx.x + st];
    }
    __syncthreads();
  }
  double mean = sh1[0] / n;
  float var = (float)(sh2[0] / n - mean * mean);
  float fm = (float)mean;
  float inv = rsqrtf(var + 1e-5f);
  float* qb = q + (size_t)(b * Cn + g * cpg) * HWl;
  for (int cl = 0; cl < cpg; ++cl) {
    float ga = gw[g * cpg + cl] * inv;
    float bb = gb[g * cpg + cl];
    for (int t = threadIdx.x; t < HWl; t += 256)
      qb[cl * HWl + t] = (base[cl * HWl + t] - fm) * ga + bb;
  }
}

// softmax over the NP=9 points: a is (B, NH*NP, h, w), per (b,head,pixel)
__global__ __launch_bounds__(256) void k_softmax9(float* __restrict__ a)
{
  int total = Bn * NHd * HWl;
  int idx = blockIdx.x * blockDim.x + threadIdx.x;
  if (idx >= total) return;
  int pix = idx % HWl;
  int head = (idx / HWl) & 3;
  int b = idx / (HWl * NHd);
  float* base = a + (size_t)(b * NHd * NPt + head * NPt) * HWl + pix;
  float v[9];
  float m = -1e30f;
#pragma unroll
  for (int p0 = 0; p0 < 9; ++p0) { v[p0] = base[p0 * HWl]; m = fmaxf(m, v[p0]); }
  float s = 0.f;
#pragma unroll
  for (int p0 = 0; p0 < 9; ++p0) { v[p0] = expf(v[p0] - m); s += v[p0]; }
  float inv = 1.f / s;
#pragma unroll
  for (int p0 = 0; p0 < 9; ++p0) base[p0 * HWl] = v[p0] * inv;
}

// ---------------------------------------------------------------------------
// Deformable sampling + attention-weighted sum.
// vals (B,128,h,w) viewed (B,NH,32,h,w); off (B,72,h,w); attn (B,36,h,w).
// grid_sample align_corners=False: x_px = sx*W/(W-1) - 0.5, clip, border pad.
// ---------------------------------------------------------------------------
__global__ __launch_bounds__(256) void k_deform(
    const float* __restrict__ vals, const float* __restrict__ off,
    const float* __restrict__ attn, float* __restrict__ outa)
{
  int total = Bn * Cn * HWl;
  int idx = blockIdx.x * blockDim.x + threadIdx.x;
  if (idx >= total) return;
  int pix = idx % HWl;
  int co = (idx / HWl) % Cn;
  int b = idx / (HWl * Cn);
  int j = pix % FW, i = pix / FW;
  int head = co >> 5;

  const float kx = (float)FW / (float)(FW - 1);
  const float ky = (float)FH / (float)(FH - 1);
  const float* vb = vals + (size_t)(b * Cn + co) * HWl;
  const float* ab = attn + (size_t)(b * NHd * NPt + head * NPt) * HWl + pix;
  const float* ob = off + (size_t)(b * NHd * NPt * 2 + head * NPt * 2) * HWl + pix;

  float acc = 0.f;
#pragma unroll
  for (int p0 = 0; p0 < 9; ++p0) {
    float ox = ob[(size_t)(p0 * 2 + 0) * HWl];
    float oy = ob[(size_t)(p0 * 2 + 1) * HWl];
    float aw = ab[(size_t)p0 * HWl];
    float xf = ((float)j + ox) * kx - 0.5f;
    float yf = ((float)i + oy) * ky - 0.5f;
    xf = fminf(fmaxf(xf, 0.f), (float)(FW - 1));
    yf = fminf(fmaxf(yf, 0.f), (float)(FH - 1));
    int x0 = (int)floorf(xf), y0 = (int)floorf(yf);
    int x1 = min(x0 + 1, FW - 1), y1 = min(y0 + 1, FH - 1);
    float fx = xf - (float)x0, fy = yf - (float)y0;
    const float* r0p = vb + y0 * FW;
    const float* r1p = vb + y1 * FW;
    float v00 = r0p[x0], v01 = r0p[x1], v10 = r1p[x0], v11 = r1p[x1];
    float vv = v00 * (1.f - fx) * (1.f - fy) + v01 * fx * (1.f - fy)
             + v10 * (1.f - fx) * fy + v11 * fx * fy;
    acc += aw * vv;
  }
  outa[(size_t)(b * Cn + co) * HWl + pix] = acc;
}

// ---------------------------------------------------------------------------
// 4x bilinear upsample (half-pixel, edge-clamped) of x (B,128,96,160)
// producing U rows [u_r0, u_r0+u_rows) at 640 width.
// ---------------------------------------------------------------------------
__global__ __launch_bounds__(256) void k_upsample(
    const float* __restrict__ x, float* __restrict__ U, int u_r0, int u_rows)
{
  const int NQ = Wh >> 2;  // 160
  int total = Bn * Cn * u_rows * NQ;
  int idx = blockIdx.x * blockDim.x + threadIdx.x;
  if (idx >= total) return;
  int q = idx % NQ;
  int t1 = idx / NQ;
  int rl = t1 % u_rows;
  int t2 = t1 / u_rows;
  int c = t2 % Cn;
  int b = t2 / Cn;
  int R = u_r0 + rl;

  float uy = ((float)R + 0.5f) * 0.25f - 0.5f;
  uy = fminf(fmaxf(uy, 0.f), (float)(FH - 1));
  int y0 = (int)floorf(uy);
  int y1 = min(y0 + 1, FH - 1);
  float fy = uy - (float)y0;

  const float* xb = x + (size_t)(b * Cn + c) * HWl;
  const float* r0p = xb + y0 * FW;
  const float* r1p = xb + y1 * FW;
  float res[4];
#pragma unroll
  for (int t = 0; t < 4; ++t) {
    int J = (q << 2) + t;
    float ux = ((float)J + 0.5f) * 0.25f - 0.5f;
    ux = fminf(fmaxf(ux, 0.f), (float)(FW - 1));
    int x0 = (int)floorf(ux);
    int x1 = min(x0 + 1, FW - 1);
    float fx = ux - (float)x0;
    float a = r0p[x0] * (1.f - fx) + r0p[x1] * fx;
    float bb = r1p[x0] * (1.f - fx) + r1p[x1] * fx;
    res[t] = a * (1.f - fy) + bb * fy;
  }
  float4 v; v.x = res[0]; v.y = res[1]; v.z = res[2]; v.w = res[3];
  float* op = U + ((size_t)(b * Cn + c) * u_rows + rl) * Wh + (q << 2);
  *reinterpret_cast<float4*>(op) = v;
}

// ---------------------------------------------------------------------------
extern "C" void kernel_launch(void* const* d_in, const int* in_sizes, int n_in,
                              void* d_out, int out_size, void* d_ws, size_t ws_size,
                              hipStream_t stream) {
  (void)in_sizes; (void)n_in; (void)out_size; (void)ws_size;
  const float* feat1  = (const float*)d_in[0];
  const float* feat2  = (const float*)d_in[1];
  const float* flowf  = (const float*)d_in[2];
  const float* flowb  = (const float*)d_in[3];
  const float* edge1  = (const float*)d_in[4];
  const float* edge2  = (const float*)d_in[5];
  const float* fuse_w0 = (const float*)d_in[6];
  const float* fuse_b0 = (const float*)d_in[7];
  const float* fuse_w1 = (const float*)d_in[8];
  const float* fuse_b1 = (const float*)d_in[9];
  const float* gn_g   = (const float*)d_in[10];
  const float* gn_b   = (const float*)d_in[11];
  const float* off_w0 = (const float*)d_in[12];
  const float* off_b0 = (const float*)d_in[13];
  const float* off_w1 = (const float*)d_in[14];
  const float* off_b1 = (const float*)d_in[15];
  const float* aw_w0  = (const float*)d_in[16];
  const float* aw_b0  = (const float*)d_in[17];
  const float* aw_w1  = (const float*)d_in[18];
  const float* aw_b1  = (const float*)d_in[19];
  const float* val_w  = (const float*)d_in[20];
  const float* val_b  = (const float*)d_in[21];
  const float* out_w  = (const float*)d_in[22];
  const float* out_b  = (const float*)d_in[23];
  const float* ffn_w0 = (const float*)d_in[24];
  const float* ffn_b0 = (const float*)d_in[25];
  const float* ffn_w1 = (const float*)d_in[26];
  const float* ffn_b1 = (const float*)d_in[27];
  const float* dec_w0 = (const float*)d_in[28];
  const float* dec_b0 = (const float*)d_in[29];
  const float* dec_w1 = (const float*)d_in[30];
  const float* dec_b1 = (const float*)d_in[31];
  const float* dec_w2 = (const float*)d_in[32];
  const float* dec_b2 = (const float*)d_in[33];
  float* out = (float*)d_out;
  float* ws = (float*)d_ws;

  // Workspace layout (floats). Total need: (2*128*15360 + 23,070,720)*4 = ~108 MB.
  float* xbuf   = ws;                                   // 2*128*HWl, lives to the end
  float* pool   = ws + (size_t)2 * Cn * HWl;
  float* fused  = pool;                                 // 2*259*HWl
  float* source = fused  + (size_t)2 * 259 * HWl;       // 2*128*HWl
  float* tmp1   = source + (size_t)2 * Cn * HWl;        // 2*128*HWl
  float* offb   = tmp1   + (size_t)2 * Cn * HWl;        // 2*72*HWl
  float* attnb  = offb   + (size_t)2 * 72 * HWl;        // 2*36*HWl
  float* valsb  = attnb  + (size_t)2 * 36 * HWl;        // 2*128*HWl
  // Aliases (lifetime-checked): fused dead after fuse-conv0; tmp1 dead after
  // fuse-conv1; source dead after vals conv; whole pool dead after FFN.
  float* t_off    = fused;
  float* t_aw     = fused + (size_t)2 * Cn * HWl;
  float* qb       = tmp1;
  float* out_attn = source;
  float* ffn_t    = fused;
  float* bufU = pool;                                   // 2*128*54*640
  float* bufA = bufU + (size_t)2 * 128 * 54 * 640;      // 2*64*52*640
  float* bufB = bufA + (size_t)2 * 64 * 52 * 640;       // 2*32*50*640

  dim3 blk(256);
  auto grd = [](long n) { return dim3((unsigned)((n + 255) / 256)); };
  const int JQl = FW / 4;   // 40
  const int JQh = Wh / 4;   // 160

  // 1. warp + concat + source
  k_warp_fuse<<<grd(2L * HWl), blk, 0, stream>>>(feat1, feat2, flowf, flowb,
                                                 edge1, edge2, fused, source);
  // 2. fuse conv0 (259->128, 3x3) + lrelu
  k_conv3x3<1><<<grd(2L * 128 * FH * JQl), blk, 0, stream>>>(fused, fuse_w0, fuse_b0, tmp1,
      2, 259, 128, FW, FH, 0, FH, 0, FH, 0, FH, 259, 128);
  // 3. fuse conv1 (128->128, 3x3) + lrelu -> x
  k_conv3x3<1><<<grd(2L * 128 * FH * JQl), blk, 0, stream>>>(tmp1, fuse_w1, fuse_b1, xbuf,
      2, 128, 128, FW, FH, 0, FH, 0, FH, 0, FH, 128, 128);
  // 4. group norm -> q
  k_groupnorm<<<dim3(16), blk, 0, stream>>>(xbuf, gn_g, gn_b, qb);
  // 5-6. offsets: grouped 3x3 + lrelu, then 1x1 -> off (72ch)
  k_conv3x3<1><<<grd(2L * 128 * FH * JQl), blk, 0, stream>>>(qb, off_w0, off_b0, t_off,
      2, 128, 128, FW, FH, 0, FH, 0, FH, 0, FH, 32, 32);
  k_conv1x1<0, 0><<<grd(2L * 72 * (HWl / 4)), blk, 0, stream>>>(t_off, off_w1, off_b1, offb,
      2, 128, 72, HWl);
  // 7-9. attention weights: grouped 3x3 + lrelu, 1x1 -> 36ch, softmax over 9
  k_conv3x3<1><<<grd(2L * 128 * FH * JQl), blk, 0, stream>>>(qb, aw_w0, aw_b0, t_aw,
      2, 128, 128, FW, FH, 0, FH, 0, FH, 0, FH, 32, 32);
  k_conv1x1<0, 0><<<grd(2L * 36 * (HWl / 4)), blk, 0, stream>>>(t_aw, aw_w1, aw_b1, attnb,
      2, 128, 36, HWl);
  k_softmax9<<<grd(2L * NHd * HWl), blk, 0, stream>>>(attnb);
  // 10. vals = 1x1(source)
  k_conv1x1<0, 0><<<grd(2L * 128 * (HWl / 4)), blk, 0, stream>>>(source, val_w, val_b, valsb,
      2, 128, 128, HWl);
  // 11. deformable sampling + weighted sum
  k_deform<<<grd(2L * 128 * HWl), blk, 0, stream>>>(valsb, offb, attnb, out_attn);
  // 12. x += 1x1(out_attn)
  k_conv1x1<0, 1><<<grd(2L * 128 * (HWl / 4)), blk, 0, stream>>>(out_attn, out_w, out_b, xbuf,
      2, 128, 128, HWl);
  // 13-14. FFN: 1x1 -> gelu -> 1x1, residual
  k_conv1x1<2, 0><<<grd(2L * 256 * (HWl / 4)), blk, 0, stream>>>(xbuf, ffn_w0, ffn_b0, ffn_t,
      2, 128, 256, HWl);
  k_conv1x1<0, 1><<<grd(2L * 128 * (HWl / 4)), blk, 0, stream>>>(ffn_t, ffn_w1, ffn_b1, xbuf,
      2, 256, 128, HWl);

  // 15. decoder in 8 row-chunks of 48 (halo recompute); upsample fused per chunk
  for (int c0 = 0; c0 < Hh; c0 += 48) {
    int c1 = c0 + 48;
    int u0 = c0 - 3 > 0 ? c0 - 3 : 0;
    int u1 = c1 + 3 < Hh ? c1 + 3 : Hh;
    int a0 = c0 - 2 > 0 ? c0 - 2 : 0;
    int a1 = c1 + 2 < Hh ? c1 + 2 : Hh;
    int b0 = c0 - 1 > 0 ? c0 - 1 : 0;
    int b1 = c1 + 1 < Hh ? c1 + 1 : Hh;
    int ur = u1 - u0, ar = a1 - a0, br = b1 - b0;
    k_upsample<<<grd(2L * 128 * ur * JQh), blk, 0, stream>>>(xbuf, bufU, u0, ur);
    k_conv3x3<1><<<grd(2L * 64 * ar * JQh), blk, 0, stream>>>(bufU, dec_w0, dec_b0, bufA,
        2, 128, 64, Wh, Hh, u0, ur, a0, ar, a0, a1, 128, 64);
    k_conv3x3<1><<<grd(2L * 32 * br * JQh), blk, 0, stream>>>(bufA, dec_w1, dec_b1, bufB,
        2, 64, 32, Wh, Hh, a0, ar, b0, br, b0, b1, 64, 32);
    k_conv3x3<3><<<grd(2L * 3 * 48 * JQh), blk, 0, stream>>>(bufB, dec_w2, dec_b2, out,
        2, 32, 3, Wh, Hh, b0, br, 0, Hh, c0, c1, 32, 3);
  }
}

// Round 2
// 5045.107 us; speedup vs baseline: 2.9112x; 2.9112x over previous
//
#include <hip/hip_runtime.h>

constexpr int Bn = 2, Cn = 128, FH = 96, FW = 160, Hh = 384, Wh = 640;
constexpr int HWl = FH * FW;   // 15360
constexpr int NHd = 4, NPt = 9;

#define DEVINL __device__ __forceinline__

template<int ACT> DEVINL float activ(float v) {
  if (ACT == 1) return v >= 0.f ? v : 0.1f * v;                       // leaky relu
  if (ACT == 2) return 0.5f * v * (1.f + erff(v * 0.70710678118654752f)); // exact gelu
  if (ACT == 3) return 1.f / (1.f + expf(-v));                        // sigmoid
  return v;
}

// ---------------------------------------------------------------------------
// Warp feat1/feat2 by (downsampled, scaled) flows; build fused concat + source.
// 8 threads per pixel, 16 channels each (grid was 480 waves before -> 3840).
// ---------------------------------------------------------------------------
__global__ __launch_bounds__(256) void k_warp_fuse2(
    const float* __restrict__ feat1, const float* __restrict__ feat2,
    const float* __restrict__ flowf, const float* __restrict__ flowb,
    const float* __restrict__ edge1, const float* __restrict__ edge2,
    float* __restrict__ fused, float* __restrict__ source)
{
  int idx = blockIdx.x * blockDim.x + threadIdx.x;
  if (idx >= Bn * 8 * HWl) return;
  int pix = idx % HWl;
  int cq = (idx / HWl) & 7;
  int b = idx / (HWl * 8);
  int j = pix % FW;
  int i = pix / FW;

  const int y4 = 4 * i + 1, x4 = 4 * j + 1;
  const float* p;
  p = flowf + (size_t)((b * 2 + 0) * Hh + y4) * Wh + x4;
  float fx1 = 0.03125f * (p[0] + p[1] + p[Wh] + p[Wh + 1]);
  p = flowf + (size_t)((b * 2 + 1) * Hh + y4) * Wh + x4;
  float fy1 = 0.03125f * (p[0] + p[1] + p[Wh] + p[Wh + 1]);
  p = flowb + (size_t)((b * 2 + 0) * Hh + y4) * Wh + x4;
  float fx2 = 0.03125f * (p[0] + p[1] + p[Wh] + p[Wh + 1]);
  p = flowb + (size_t)((b * 2 + 1) * Hh + y4) * Wh + x4;
  float fy2 = 0.03125f * (p[0] + p[1] + p[Wh] + p[Wh + 1]);

  float sx1 = fminf(fmaxf((float)j + fx1, 0.f), (float)(FW - 1));
  float sy1 = fminf(fmaxf((float)i + fy1, 0.f), (float)(FH - 1));
  float sx2 = fminf(fmaxf((float)j + fx2, 0.f), (float)(FW - 1));
  float sy2 = fminf(fmaxf((float)i + fy2, 0.f), (float)(FH - 1));

  int x10 = (int)floorf(sx1), y10 = (int)floorf(sy1);
  int x11 = min(x10 + 1, FW - 1), y11 = min(y10 + 1, FH - 1);
  float wx1 = sx1 - (float)x10, wy1 = sy1 - (float)y10;
  int x20 = (int)floorf(sx2), y20 = (int)floorf(sy2);
  int x21 = min(x20 + 1, FW - 1), y21 = min(y20 + 1, FH - 1);
  float wx2 = sx2 - (float)x20, wy2 = sy2 - (float)y20;

  float a00 = (1.f - wx1) * (1.f - wy1), a01 = wx1 * (1.f - wy1);
  float a10 = (1.f - wx1) * wy1,         a11 = wx1 * wy1;
  float c00 = (1.f - wx2) * (1.f - wy2), c01 = wx2 * (1.f - wy2);
  float c10 = (1.f - wx2) * wy2,         c11 = wx2 * wy2;
  int o00 = y10 * FW + x10, o01 = y10 * FW + x11, o10 = y11 * FW + x10, o11 = y11 * FW + x11;
  int q00 = y20 * FW + x20, q01 = y20 * FW + x21, q10 = y21 * FW + x20, q11 = y21 * FW + x21;

  if (cq == 0) {
    p = edge1 + (size_t)(b * Hh + y4) * Wh + x4;
    fused[(size_t)(b * 259 + 256) * HWl + pix] = 0.25f * (p[0] + p[1] + p[Wh] + p[Wh + 1]);
    p = edge2 + (size_t)(b * Hh + y4) * Wh + x4;
    fused[(size_t)(b * 259 + 257) * HWl + pix] = 0.25f * (p[0] + p[1] + p[Wh] + p[Wh + 1]);
    fused[(size_t)(b * 259 + 258) * HWl + pix] = 0.5f;  // tmap = T
  }

  int c0 = cq * 16;
  for (int c = c0; c < c0 + 16; ++c) {
    const float* f1 = feat1 + (size_t)(b * Cn + c) * HWl;
    const float* f2 = feat2 + (size_t)(b * Cn + c) * HWl;
    float v1 = f1[o00] * a00 + f1[o01] * a01 + f1[o10] * a10 + f1[o11] * a11;
    float v2 = f2[q00] * c00 + f2[q01] * c01 + f2[q10] * c10 + f2[q11] * c11;
    fused[(size_t)(b * 259 + c) * HWl + pix] = v1;
    fused[(size_t)(b * 259 + 128 + c) * HWl + pix] = v2;
    source[(size_t)(b * Cn + c) * HWl + pix] = 0.5f * (v1 + v2);
  }
}

// ---------------------------------------------------------------------------
// 3x3 conv with COT output channels per thread. co-tile from blockIdx.y only
// => weight/bias pointers are wave-uniform => scalar (s_load) path.
// in buffer holds global rows [in_r0, +in_rows); out holds [out_r0, +out_rows).
// Computes global output rows [ogr0, ogr1). Rows outside [0,Htot) are zero-pad.
// grid.x covers (ogr1-ogr0)*W/4 threads; grid.y = B * (Cout/COT).
// ---------------------------------------------------------------------------
template<int ACT, int COT>
__global__ __launch_bounds__(256) void k_conv3x3b(
    const float* __restrict__ in, const float* __restrict__ wt,
    const float* __restrict__ bias, float* __restrict__ out,
    int Cin, int Cout, int W, int Htot,
    int in_r0, int in_rows, int out_r0, int out_rows,
    int ogr0, int ogr1, int cin_g, int cout_g)
{
  int JQ = W >> 2;
  int nrows = ogr1 - ogr0;
  int per = nrows * JQ;
  int idx = blockIdx.x * blockDim.x + threadIdx.x;
  if (idx >= per) return;
  int cotiles = Cout / COT;
  int cot = blockIdx.y % cotiles;
  int b = blockIdx.y / cotiles;
  int co0 = cot * COT;
  int q = idx % JQ;
  int r = idx / JQ + ogr0;
  int j0 = q << 2;
  bool has_l = (j0 > 0), has_r = (j0 + 4 < W);

  float acc[COT][4];
#pragma unroll
  for (int cc = 0; cc < COT; ++cc) {
    float bv = bias[co0 + cc];
    acc[cc][0] = bv; acc[cc][1] = bv; acc[cc][2] = bv; acc[cc][3] = bv;
  }
  int cib = (co0 / cout_g) * cin_g;
  const float* wb0 = wt + (size_t)co0 * cin_g * 9;

  for (int cl = 0; cl < cin_g; ++cl) {
    float4 m[3]; float v0[3], v5[3];
    const float* ibase = in + (size_t)((b * Cin + cib + cl) * in_rows - in_r0) * W;
#pragma unroll
    for (int dy = 0; dy < 3; ++dy) {
      int gr = r + dy - 1;
      if (gr >= 0 && gr < Htot) {
        const float* ip = ibase + (size_t)gr * W;
        m[dy] = *reinterpret_cast<const float4*>(ip + j0);
        v0[dy] = has_l ? ip[j0 - 1] : 0.f;
        v5[dy] = has_r ? ip[j0 + 4] : 0.f;
      } else {
        m[dy] = make_float4(0.f, 0.f, 0.f, 0.f); v0[dy] = 0.f; v5[dy] = 0.f;
      }
    }
#pragma unroll
    for (int cc = 0; cc < COT; ++cc) {
      const float* wp = wb0 + ((size_t)cc * cin_g + cl) * 9;
#pragma unroll
      for (int dy = 0; dy < 3; ++dy) {
        float wa = wp[dy * 3], wb = wp[dy * 3 + 1], wc = wp[dy * 3 + 2];
        acc[cc][0] += wa * v0[dy]   + wb * m[dy].x + wc * m[dy].y;
        acc[cc][1] += wa * m[dy].x  + wb * m[dy].y + wc * m[dy].z;
        acc[cc][2] += wa * m[dy].y  + wb * m[dy].z + wc * m[dy].w;
        acc[cc][3] += wa * m[dy].z  + wb * m[dy].w + wc * v5[dy];
      }
    }
  }
#pragma unroll
  for (int cc = 0; cc < COT; ++cc) {
    float4 res;
    res.x = activ<ACT>(acc[cc][0]); res.y = activ<ACT>(acc[cc][1]);
    res.z = activ<ACT>(acc[cc][2]); res.w = activ<ACT>(acc[cc][3]);
    float* op = out + ((size_t)(b * Cout + co0 + cc) * out_rows + (r - out_r0)) * W + j0;
    *reinterpret_cast<float4*>(op) = res;
  }
}

// ---------------------------------------------------------------------------
// 1x1 conv, COT output channels per thread; optional residual add (RES).
// grid.x covers HW/4; grid.y = B * (Cout/COT).
// ---------------------------------------------------------------------------
template<int ACT, int RES, int COT>
__global__ __launch_bounds__(256) void k_conv1x1b(
    const float* __restrict__ in, const float* __restrict__ wt,
    const float* __restrict__ bias, float* __restrict__ out,
    int Cin, int Cout, int HW)
{
  int NQ = HW >> 2;
  int idx = blockIdx.x * blockDim.x + threadIdx.x;
  if (idx >= NQ) return;
  int cotiles = Cout / COT;
  int cot = blockIdx.y % cotiles;
  int b = blockIdx.y / cotiles;
  int co0 = cot * COT;
  int j0 = idx << 2;

  float acc[COT][4];
#pragma unroll
  for (int cc = 0; cc < COT; ++cc) {
    float bv = bias[co0 + cc];
    acc[cc][0] = bv; acc[cc][1] = bv; acc[cc][2] = bv; acc[cc][3] = bv;
  }
  const float* ip = in + (size_t)b * Cin * HW + j0;
  for (int ci = 0; ci < Cin; ++ci) {
    float4 v = *reinterpret_cast<const float4*>(ip + (size_t)ci * HW);
#pragma unroll
    for (int cc = 0; cc < COT; ++cc) {
      float wv = wt[(size_t)(co0 + cc) * Cin + ci];
      acc[cc][0] += wv * v.x; acc[cc][1] += wv * v.y;
      acc[cc][2] += wv * v.z; acc[cc][3] += wv * v.w;
    }
  }
#pragma unroll
  for (int cc = 0; cc < COT; ++cc) {
    float4 res;
    res.x = activ<ACT>(acc[cc][0]); res.y = activ<ACT>(acc[cc][1]);
    res.z = activ<ACT>(acc[cc][2]); res.w = activ<ACT>(acc[cc][3]);
    float* op = out + (size_t)(b * Cout + co0 + cc) * HW + j0;
    if (RES) {
      float4 pv = *reinterpret_cast<const float4*>(op);
      res.x += pv.x; res.y += pv.y; res.z += pv.z; res.w += pv.w;
    }
    *reinterpret_cast<float4*>(op) = res;
  }
}

// ---------------------------------------------------------------------------
// GroupNorm two-stage. part: 128 blocks = (b,g,slice of 8); apply: grid-stride.
// ---------------------------------------------------------------------------
__global__ __launch_bounds__(256) void k_gn_part(
    const float* __restrict__ x, float* __restrict__ part)
{
  int s = blockIdx.x & 7;
  int g = (blockIdx.x >> 3) & 7;
  int b = blockIdx.x >> 6;
  const float* base = x + (size_t)(b * Cn + g * 16) * HWl;
  const int chunk = 16 * HWl / 8;   // 30720
  float sum = 0.f, ss = 0.f;
  for (int t = s * chunk + threadIdx.x; t < (s + 1) * chunk; t += 256) {
    float v = base[t];
    sum += v; ss += v * v;
  }
  __shared__ float sh1[256], sh2[256];
  sh1[threadIdx.x] = sum; sh2[threadIdx.x] = ss;
  __syncthreads();
  for (int st = 128; st > 0; st >>= 1) {
    if (threadIdx.x < st) {
      sh1[threadIdx.x] += sh1[threadIdx.x + st];
      sh2[threadIdx.x] += sh2[threadIdx.x + st];
    }
    __syncthreads();
  }
  if (threadIdx.x == 0) {
    part[blockIdx.x * 2] = sh1[0];
    part[blockIdx.x * 2 + 1] = sh2[0];
  }
}

__global__ __launch_bounds__(256) void k_gn_apply(
    const float* __restrict__ x, const float* __restrict__ gw,
    const float* __restrict__ gb, const float* __restrict__ part,
    float* __restrict__ q)
{
  int idx = blockIdx.x * blockDim.x + threadIdx.x;
  int total4 = Bn * Cn * HWl / 4;
  if (idx >= total4) return;
  int e = idx << 2;
  int c = (e / HWl) % Cn;
  int b = e / (HWl * Cn);
  int g = c >> 4;
  const float* pp = part + (size_t)((b * 8 + g) * 8) * 2;
  float sum = 0.f, ss = 0.f;
#pragma unroll
  for (int s = 0; s < 8; ++s) { sum += pp[s * 2]; ss += pp[s * 2 + 1]; }
  const float n = 16.f * HWl;
  float mean = sum / n;
  float var = ss / n - mean * mean;
  float inv = rsqrtf(var + 1e-5f);
  float ga = gw[c] * inv;
  float bb = gb[c];
  float4 v = *reinterpret_cast<const float4*>(x + e);
  float4 r;
  r.x = (v.x - mean) * ga + bb; r.y = (v.y - mean) * ga + bb;
  r.z = (v.z - mean) * ga + bb; r.w = (v.w - mean) * ga + bb;
  *reinterpret_cast<float4*>(q + e) = r;
}

// softmax over the NP=9 points: a is (B, NH*NP, h, w), per (b,head,pixel)
__global__ __launch_bounds__(256) void k_softmax9(float* __restrict__ a)
{
  int total = Bn * NHd * HWl;
  int idx = blockIdx.x * blockDim.x + threadIdx.x;
  if (idx >= total) return;
  int pix = idx % HWl;
  int head = (idx / HWl) & 3;
  int b = idx / (HWl * NHd);
  float* base = a + (size_t)(b * NHd * NPt + head * NPt) * HWl + pix;
  float v[9];
  float m = -1e30f;
#pragma unroll
  for (int p0 = 0; p0 < 9; ++p0) { v[p0] = base[p0 * HWl]; m = fmaxf(m, v[p0]); }
  float s = 0.f;
#pragma unroll
  for (int p0 = 0; p0 < 9; ++p0) { v[p0] = expf(v[p0] - m); s += v[p0]; }
  float inv = 1.f / s;
#pragma unroll
  for (int p0 = 0; p0 < 9; ++p0) base[p0 * HWl] = v[p0] * inv;
}

// Transpose vals (B,128,HW) -> (B,4head,HW,32ch)
__global__ __launch_bounds__(256) void k_tr32(
    const float* __restrict__ v, float* __restrict__ vt)
{
  int idx = blockIdx.x * blockDim.x + threadIdx.x;
  if (idx >= Bn * NHd * HWl) return;
  int pix = idx % HWl;
  int head = (idx / HWl) & 3;
  int b = idx / (HWl * NHd);
  const float* src = v + (size_t)(b * Cn + head * 32) * HWl + pix;
  float tmp[32];
#pragma unroll
  for (int c = 0; c < 32; ++c) tmp[c] = src[(size_t)c * HWl];
  float* dst = vt + ((size_t)(b * NHd + head) * HWl + pix) * 32;
#pragma unroll
  for (int k = 0; k < 8; ++k) {
    float4 o; o.x = tmp[k*4]; o.y = tmp[k*4+1]; o.z = tmp[k*4+2]; o.w = tmp[k*4+3];
    *reinterpret_cast<float4*>(dst + k * 4) = o;
  }
}

// ---------------------------------------------------------------------------
// Deformable sampling: one thread per (b,head,pixel), all 32 head-channels.
// vals_t is (B,4,HW,32). grid_sample align_corners=False, border padding.
// ---------------------------------------------------------------------------
__global__ __launch_bounds__(256) void k_deform2(
    const float* __restrict__ vals_t, const float* __restrict__ off,
    const float* __restrict__ attn, float* __restrict__ outa)
{
  int idx = blockIdx.x * blockDim.x + threadIdx.x;
  if (idx >= Bn * NHd * HWl) return;
  int pix = idx % HWl;
  int head = (idx / HWl) & 3;
  int b = idx / (HWl * NHd);
  int j = pix % FW, i = pix / FW;

  const float kx = (float)FW / (float)(FW - 1);
  const float ky = (float)FH / (float)(FH - 1);
  const float* vb = vals_t + (size_t)(b * NHd + head) * HWl * 32;
  const float* ab = attn + ((size_t)b * 36 + head * 9) * HWl + pix;
  const float* ob = off + ((size_t)b * 72 + head * 18) * HWl + pix;

  float4 acc[8];
#pragma unroll
  for (int k = 0; k < 8; ++k) acc[k] = make_float4(0.f, 0.f, 0.f, 0.f);

#pragma unroll
  for (int p0 = 0; p0 < 9; ++p0) {
    float ox = ob[(size_t)(p0 * 2) * HWl];
    float oy = ob[(size_t)(p0 * 2 + 1) * HWl];
    float aw = ab[(size_t)p0 * HWl];
    float xf = ((float)j + ox) * kx - 0.5f;
    float yf = ((float)i + oy) * ky - 0.5f;
    xf = fminf(fmaxf(xf, 0.f), (float)(FW - 1));
    yf = fminf(fmaxf(yf, 0.f), (float)(FH - 1));
    int x0 = (int)floorf(xf), y0 = (int)floorf(yf);
    int x1 = min(x0 + 1, FW - 1), y1 = min(y0 + 1, FH - 1);
    float fx = xf - (float)x0, fy = yf - (float)y0;
    float w00 = aw * (1.f - fx) * (1.f - fy);
    float w01 = aw * fx * (1.f - fy);
    float w10 = aw * (1.f - fx) * fy;
    float w11 = aw * fx * fy;
    const float4* c00 = reinterpret_cast<const float4*>(vb + (size_t)(y0 * FW + x0) * 32);
    const float4* c01 = reinterpret_cast<const float4*>(vb + (size_t)(y0 * FW + x1) * 32);
    const float4* c10 = reinterpret_cast<const float4*>(vb + (size_t)(y1 * FW + x0) * 32);
    const float4* c11 = reinterpret_cast<const float4*>(vb + (size_t)(y1 * FW + x1) * 32);
#pragma unroll
    for (int k = 0; k < 8; ++k) {
      float4 a = c00[k], bb = c01[k], cc = c10[k], dd = c11[k];
      acc[k].x += w00 * a.x + w01 * bb.x + w10 * cc.x + w11 * dd.x;
      acc[k].y += w00 * a.y + w01 * bb.y + w10 * cc.y + w11 * dd.y;
      acc[k].z += w00 * a.z + w01 * bb.z + w10 * cc.z + w11 * dd.z;
      acc[k].w += w00 * a.w + w01 * bb.w + w10 * cc.w + w11 * dd.w;
    }
  }
  float* op = outa + (size_t)(b * Cn + head * 32) * HWl + pix;
#pragma unroll
  for (int k = 0; k < 8; ++k) {
    op[(size_t)(k * 4 + 0) * HWl] = acc[k].x;
    op[(size_t)(k * 4 + 1) * HWl] = acc[k].y;
    op[(size_t)(k * 4 + 2) * HWl] = acc[k].z;
    op[(size_t)(k * 4 + 3) * HWl] = acc[k].w;
  }
}

// ---------------------------------------------------------------------------
// 4x bilinear upsample (half-pixel, edge-clamped) of x (B,128,96,160)
// producing U rows [u_r0, u_r0+u_rows) at 640 width.
// ---------------------------------------------------------------------------
__global__ __launch_bounds__(256) void k_upsample(
    const float* __restrict__ x, float* __restrict__ U, int u_r0, int u_rows)
{
  const int NQ = Wh >> 2;  // 160
  int total = Bn * Cn * u_rows * NQ;
  int idx = blockIdx.x * blockDim.x + threadIdx.x;
  if (idx >= total) return;
  int q = idx % NQ;
  int t1 = idx / NQ;
  int rl = t1 % u_rows;
  int t2 = t1 / u_rows;
  int c = t2 % Cn;
  int b = t2 / Cn;
  int R = u_r0 + rl;

  float uy = ((float)R + 0.5f) * 0.25f - 0.5f;
  uy = fminf(fmaxf(uy, 0.f), (float)(FH - 1));
  int y0 = (int)floorf(uy);
  int y1 = min(y0 + 1, FH - 1);
  float fy = uy - (float)y0;

  const float* xb = x + (size_t)(b * Cn + c) * HWl;
  const float* r0p = xb + y0 * FW;
  const float* r1p = xb + y1 * FW;
  float res[4];
#pragma unroll
  for (int t = 0; t < 4; ++t) {
    int J = (q << 2) + t;
    float ux = ((float)J + 0.5f) * 0.25f - 0.5f;
    ux = fminf(fmaxf(ux, 0.f), (float)(FW - 1));
    int x0 = (int)floorf(ux);
    int x1 = min(x0 + 1, FW - 1);
    float fx = ux - (float)x0;
    float a = r0p[x0] * (1.f - fx) + r0p[x1] * fx;
    float bb = r1p[x0] * (1.f - fx) + r1p[x1] * fx;
    res[t] = a * (1.f - fy) + bb * fy;
  }
  float4 v; v.x = res[0]; v.y = res[1]; v.z = res[2]; v.w = res[3];
  float* op = U + ((size_t)(b * Cn + c) * u_rows + rl) * Wh + (q << 2);
  *reinterpret_cast<float4*>(op) = v;
}

// ---------------------------------------------------------------------------
extern "C" void kernel_launch(void* const* d_in, const int* in_sizes, int n_in,
                              void* d_out, int out_size, void* d_ws, size_t ws_size,
                              hipStream_t stream) {
  (void)in_sizes; (void)n_in; (void)out_size; (void)ws_size;
  const float* feat1  = (const float*)d_in[0];
  const float* feat2  = (const float*)d_in[1];
  const float* flowf  = (const float*)d_in[2];
  const float* flowb  = (const float*)d_in[3];
  const float* edge1  = (const float*)d_in[4];
  const float* edge2  = (const float*)d_in[5];
  const float* fuse_w0 = (const float*)d_in[6];
  const float* fuse_b0 = (const float*)d_in[7];
  const float* fuse_w1 = (const float*)d_in[8];
  const float* fuse_b1 = (const float*)d_in[9];
  const float* gn_g   = (const float*)d_in[10];
  const float* gn_b   = (const float*)d_in[11];
  const float* off_w0 = (const float*)d_in[12];
  const float* off_b0 = (const float*)d_in[13];
  const float* off_w1 = (const float*)d_in[14];
  const float* off_b1 = (const float*)d_in[15];
  const float* aw_w0  = (const float*)d_in[16];
  const float* aw_b0  = (const float*)d_in[17];
  const float* aw_w1  = (const float*)d_in[18];
  const float* aw_b1  = (const float*)d_in[19];
  const float* val_w  = (const float*)d_in[20];
  const float* val_b  = (const float*)d_in[21];
  const float* out_w  = (const float*)d_in[22];
  const float* out_b  = (const float*)d_in[23];
  const float* ffn_w0 = (const float*)d_in[24];
  const float* ffn_b0 = (const float*)d_in[25];
  const float* ffn_w1 = (const float*)d_in[26];
  const float* ffn_b1 = (const float*)d_in[27];
  const float* dec_w0 = (const float*)d_in[28];
  const float* dec_b0 = (const float*)d_in[29];
  const float* dec_w1 = (const float*)d_in[30];
  const float* dec_b1 = (const float*)d_in[31];
  const float* dec_w2 = (const float*)d_in[32];
  const float* dec_b2 = (const float*)d_in[33];
  float* out = (float*)d_out;
  float* ws = (float*)d_ws;

  // Workspace layout (floats), ~108 MB total, same as R1.
  float* xbuf   = ws;                                   // 2*128*HWl
  float* pool   = ws + (size_t)2 * Cn * HWl;
  float* fused  = pool;                                 // 2*259*HWl
  float* source = fused  + (size_t)2 * 259 * HWl;       // 2*128*HWl
  float* tmp1   = source + (size_t)2 * Cn * HWl;        // 2*128*HWl
  float* offb   = tmp1   + (size_t)2 * Cn * HWl;        // 2*72*HWl
  float* attnb  = offb   + (size_t)2 * 72 * HWl;        // 2*36*HWl
  float* valsb  = attnb  + (size_t)2 * 36 * HWl;        // 2*128*HWl
  // Aliases (lifetimes checked):
  float* t_off    = fused;                              // dead after off-1x1
  float* t_aw     = fused + (size_t)2 * Cn * HWl;       // dead after aw-1x1
  float* qb       = tmp1;
  float* out_attn = source;                             // source dead after vals conv
  float* vals_t   = fused;                              // after t_off dead; dead after deform
  float* ffn_t    = fused;                              // after vals_t dead
  float* gnws     = offb;                               // offb written later (step 6)
  float* bufU = pool;                                   // 2*128*54*640
  float* bufA = bufU + (size_t)2 * 128 * 54 * 640;      // 2*64*52*640
  float* bufB = bufA + (size_t)2 * 64 * 52 * 640;       // 2*32*50*640

  dim3 blk(256);
  auto grd = [](long n) { return dim3((unsigned)((n + 255) / 256)); };
  auto g2 = [](long nx, int ny) { return dim3((unsigned)((nx + 255) / 256), (unsigned)ny); };
  const int NQl = HWl / 4;  // 3840

  // 1. warp + concat + source
  k_warp_fuse2<<<grd(2L * 8 * HWl), blk, 0, stream>>>(feat1, feat2, flowf, flowb,
                                                      edge1, edge2, fused, source);
  // 2. fuse conv0 (259->128) + lrelu
  k_conv3x3b<1, 8><<<g2(96L * 40, 2 * 16), blk, 0, stream>>>(fused, fuse_w0, fuse_b0, tmp1,
      259, 128, FW, FH, 0, FH, 0, FH, 0, FH, 259, 128);
  // 3. fuse conv1 (128->128) + lrelu -> xbuf  (note: qb aliases tmp1; write xbuf first)
  k_conv3x3b<1, 8><<<g2(96L * 40, 2 * 16), blk, 0, stream>>>(tmp1, fuse_w1, fuse_b1, xbuf,
      128, 128, FW, FH, 0, FH, 0, FH, 0, FH, 128, 128);
  // 4. group norm -> qb
  k_gn_part<<<dim3(128), blk, 0, stream>>>(xbuf, gnws);
  k_gn_apply<<<grd(2L * Cn * HWl / 4), blk, 0, stream>>>(xbuf, gn_g, gn_b, gnws, qb);
  // 5-6. offsets: grouped 3x3 + lrelu, then 1x1 -> offb (72ch)
  k_conv3x3b<1, 8><<<g2(96L * 40, 2 * 16), blk, 0, stream>>>(qb, off_w0, off_b0, t_off,
      128, 128, FW, FH, 0, FH, 0, FH, 0, FH, 32, 32);
  k_conv1x1b<0, 0, 8><<<g2(NQl, 2 * 9), blk, 0, stream>>>(t_off, off_w1, off_b1, offb,
      128, 72, HWl);
  // 7-8. attention weights: grouped 3x3 + lrelu, 1x1 -> 36ch, softmax
  k_conv3x3b<1, 8><<<g2(96L * 40, 2 * 16), blk, 0, stream>>>(qb, aw_w0, aw_b0, t_aw,
      128, 128, FW, FH, 0, FH, 0, FH, 0, FH, 32, 32);
  k_conv1x1b<0, 0, 4><<<g2(NQl, 2 * 9), blk, 0, stream>>>(t_aw, aw_w1, aw_b1, attnb,
      128, 36, HWl);
  k_softmax9<<<grd(2L * NHd * HWl), blk, 0, stream>>>(attnb);
  // 9. vals = 1x1(source); transpose to (B,4,HW,32)
  k_conv1x1b<0, 0, 8><<<g2(NQl, 2 * 16), blk, 0, stream>>>(source, val_w, val_b, valsb,
      128, 128, HWl);
  k_tr32<<<grd(2L * NHd * HWl), blk, 0, stream>>>(valsb, vals_t);
  // 10. deformable sampling + weighted sum -> out_attn (NCHW)
  k_deform2<<<grd(2L * NHd * HWl), blk, 0, stream>>>(vals_t, offb, attnb, out_attn);
  // 11. xbuf += 1x1(out_attn)
  k_conv1x1b<0, 1, 8><<<g2(NQl, 2 * 16), blk, 0, stream>>>(out_attn, out_w, out_b, xbuf,
      128, 128, HWl);
  // 12-13. FFN: 1x1 -> gelu -> 1x1, residual
  k_conv1x1b<2, 0, 8><<<g2(NQl, 2 * 32), blk, 0, stream>>>(xbuf, ffn_w0, ffn_b0, ffn_t,
      128, 256, HWl);
  k_conv1x1b<0, 1, 8><<<g2(NQl, 2 * 16), blk, 0, stream>>>(ffn_t, ffn_w1, ffn_b1, xbuf,
      256, 128, HWl);

  // 14. decoder in 8 row-chunks of 48 (halo recompute); upsample fused per chunk
  for (int c0 = 0; c0 < Hh; c0 += 48) {
    int c1 = c0 + 48;
    int u0 = c0 - 3 > 0 ? c0 - 3 : 0;
    int u1 = c1 + 3 < Hh ? c1 + 3 : Hh;
    int a0 = c0 - 2 > 0 ? c0 - 2 : 0;
    int a1 = c1 + 2 < Hh ? c1 + 2 : Hh;
    int b0 = c0 - 1 > 0 ? c0 - 1 : 0;
    int b1 = c1 + 1 < Hh ? c1 + 1 : Hh;
    int ur = u1 - u0, ar = a1 - a0, br = b1 - b0;
    k_upsample<<<grd(2L * 128 * ur * 160), blk, 0, stream>>>(xbuf, bufU, u0, ur);
    k_conv3x3b<1, 8><<<g2((long)ar * 160, 2 * 8), blk, 0, stream>>>(bufU, dec_w0, dec_b0, bufA,
        128, 64, Wh, Hh, u0, ur, a0, ar, a0, a1, 128, 64);
    k_conv3x3b<1, 8><<<g2((long)br * 160, 2 * 4), blk, 0, stream>>>(bufA, dec_w1, dec_b1, bufB,
        64, 32, Wh, Hh, a0, ar, b0, br, b0, b1, 64, 32);
    k_conv3x3b<3, 3><<<g2(48L * 160, 2 * 1), blk, 0, stream>>>(bufB, dec_w2, dec_b2, out,
        32, 3, Wh, Hh, b0, br, 0, Hh, c0, c1, 32, 3);
  }
}